// Round 4
// baseline (117.246 us; speedup 1.0000x reference)
//
#include <hip/hip_runtime.h>

// GLIF3 neuron update, B = 8388608, M = 2. Memory-bound streaming kernel.
// Round 4: round-2 structure + NON-TEMPORAL stores (fixed: use clang
// ext_vector_type for the builtin; HIP_vector_type<float,4> is rejected).
// Rationale: R1 vs R2 identical dur (116 us) across very different schedules
// -> bandwidth-bound at ~5.2 TB/s combined fabric traffic (604 MB / call).
// Outputs (134 MB) pollute L3 each replay, halving input residency
// (FETCH=230 MB of 470 MB input). NT stores free L3 for inputs.
//
// Numerics: precise expf, IEEE div, fp contract off -> matches numpy f32
// per-op rounding so the hard spike threshold doesn't flip.

typedef float vfloat4 __attribute__((ext_vector_type(4)));

__device__ __forceinline__ void nt_store4(float4 val, float4* ptr) {
    vfloat4 v;
    v.x = val.x; v.y = val.y; v.z = val.z; v.w = val.w;
    __builtin_nontemporal_store(v, (vfloat4*)ptr);
}

__device__ __forceinline__ void glif1(float v, float x, float th, float rs,
                                      float re, float cm, float tau, float nr,
                                      float ia0, float ia1, float k0, float k1,
                                      float am0, float am1,
                                      float& vp, float& ip0, float& ip1, float& s)
{
#pragma clang fp contract(off)
    float a = expf(-1.0f / tau);                    // DT = 1
    float isum = ia0 + ia1;
    float v_inf = re + (tau * (x + isum)) / cm;     // python eval order
    float v_prime = v_inf + (v - v_inf) * a;
    s = (v_prime > th) ? nr : 0.0f;                 // (a-b)>0 <=> a>b in IEEE
    vp = v_prime - (th - rs) * s;                   // soft reset
    ip0 = ia0 * expf(-k0) + am0 * s;
    ip1 = ia1 * expf(-k1) + am1 * s;
}

__device__ __forceinline__ void compute4(
    float4 v, float4 x, float4 th, float4 rs, float4 re, float4 cm,
    float4 tau, float4 nr, float4 ia0, float4 ia1, float4 k0, float4 k1,
    float4 am0, float4 am1,
    float4& vp, float4& ipA, float4& ipB, float4& s)
{
    // (B,2) interleave: ia0 = {n0m0, n0m1, n1m0, n1m1}, ia1 = {n2m0, n2m1, n3m0, n3m1}
    glif1(v.x, x.x, th.x, rs.x, re.x, cm.x, tau.x, nr.x,
          ia0.x, ia0.y, k0.x, k0.y, am0.x, am0.y, vp.x, ipA.x, ipA.y, s.x);
    glif1(v.y, x.y, th.y, rs.y, re.y, cm.y, tau.y, nr.y,
          ia0.z, ia0.w, k0.z, k0.w, am0.z, am0.w, vp.y, ipA.z, ipA.w, s.y);
    glif1(v.z, x.z, th.z, rs.z, re.z, cm.z, tau.z, nr.z,
          ia1.x, ia1.y, k1.x, k1.y, am1.x, am1.y, vp.z, ipB.x, ipB.y, s.z);
    glif1(v.w, x.w, th.w, rs.w, re.w, cm.w, tau.w, nr.w,
          ia1.z, ia1.w, k1.z, k1.w, am1.z, am1.w, vp.w, ipB.z, ipB.w, s.w);
}

__global__ __launch_bounds__(256) void glif3_kernel(
    const float4* __restrict__ v_in,
    const float4* __restrict__ iasc_in,
    const float4* __restrict__ x_in,
    const float4* __restrict__ vth_in,
    const float4* __restrict__ vreset_in,
    const float4* __restrict__ vrest_in,
    const float4* __restrict__ cm_in,
    const float4* __restrict__ tau_in,
    const float4* __restrict__ k_in,
    const float4* __restrict__ amps_in,
    const float4* __restrict__ nref_in,
    float4* __restrict__ vpost_out,
    float4* __restrict__ ipost_out,
    float4* __restrict__ s_out,
    int n4)
{
    int t = threadIdx.x;
    int e0 = blockIdx.x * 512 + t;      // chunk A (float4 index into B/4 space)
    int e1 = e0 + 256;                  // chunk B

    // ---- issue ALL 28 loads before any use ----
    float4 Av  = v_in[e0],        Bv  = v_in[e1];
    float4 Ax  = x_in[e0],        Bx  = x_in[e1];
    float4 Ath = vth_in[e0],      Bth = vth_in[e1];
    float4 Ars = vreset_in[e0],   Brs = vreset_in[e1];
    float4 Are = vrest_in[e0],    Bre = vrest_in[e1];
    float4 Acm = cm_in[e0],       Bcm = cm_in[e1];
    float4 Atu = tau_in[e0],      Btu = tau_in[e1];
    float4 Anr = nref_in[e0],     Bnr = nref_in[e1];
    float4 Aia0 = iasc_in[2 * e0],     Aia1 = iasc_in[2 * e0 + 1];
    float4 Bia0 = iasc_in[2 * e1],     Bia1 = iasc_in[2 * e1 + 1];
    float4 Ak0  = k_in[2 * e0],        Ak1  = k_in[2 * e0 + 1];
    float4 Bk0  = k_in[2 * e1],        Bk1  = k_in[2 * e1 + 1];
    float4 Aam0 = amps_in[2 * e0],     Aam1 = amps_in[2 * e0 + 1];
    float4 Bam0 = amps_in[2 * e1],     Bam1 = amps_in[2 * e1 + 1];

    __builtin_amdgcn_sched_barrier(0);  // keep loads above, compute below

    float4 vp, ipA, ipB, s;

    compute4(Av, Ax, Ath, Ars, Are, Acm, Atu, Anr,
             Aia0, Aia1, Ak0, Ak1, Aam0, Aam1, vp, ipA, ipB, s);
    nt_store4(vp,  &vpost_out[e0]);
    nt_store4(ipA, &ipost_out[2 * e0]);
    nt_store4(ipB, &ipost_out[2 * e0 + 1]);
    nt_store4(s,   &s_out[e0]);

    compute4(Bv, Bx, Bth, Brs, Bre, Bcm, Btu, Bnr,
             Bia0, Bia1, Bk0, Bk1, Bam0, Bam1, vp, ipA, ipB, s);
    nt_store4(vp,  &vpost_out[e1]);
    nt_store4(ipA, &ipost_out[2 * e1]);
    nt_store4(ipB, &ipost_out[2 * e1 + 1]);
    nt_store4(s,   &s_out[e1]);
}

extern "C" void kernel_launch(void* const* d_in, const int* in_sizes, int n_in,
                              void* d_out, int out_size, void* d_ws, size_t ws_size,
                              hipStream_t stream) {
    const float4* v     = (const float4*)d_in[0];
    const float4* iasc  = (const float4*)d_in[1];
    const float4* x     = (const float4*)d_in[2];
    const float4* vth   = (const float4*)d_in[3];
    const float4* vrst  = (const float4*)d_in[4];
    const float4* vrest = (const float4*)d_in[5];
    const float4* cm    = (const float4*)d_in[6];
    const float4* tau   = (const float4*)d_in[7];
    const float4* k     = (const float4*)d_in[8];
    const float4* amps  = (const float4*)d_in[9];
    const float4* nref  = (const float4*)d_in[10];

    const int B = in_sizes[0];            // 8388608
    float* out = (float*)d_out;
    float4* vpost = (float4*)out;                       // [0, B)
    float4* ipost = (float4*)(out + (size_t)B);         // [B, 3B)
    float4* sout  = (float4*)(out + (size_t)3 * B);     // [3B, 4B)

    const int n4 = B / 4;                               // 2097152
    const int block = 256;
    const int grid = n4 / (2 * block);                  // 4096 (exact)

    glif3_kernel<<<grid, block, 0, stream>>>(v, iasc, x, vth, vrst, vrest, cm,
                                             tau, k, amps, nref,
                                             vpost, ipost, sout, n4);
}